// Round 1
// 348.772 us; speedup vs baseline: 1.0357x; 1.0357x over previous
//
#include <hip/hip_runtime.h>
#include <stdint.h>

#define HW        (1024 * 1024)
#define KIDS      64
#define NCANDS    16
#define BCC       76          /* B*C = 4*19 */
#define EPSF      1e-6f
#define MARGINF   1.0f
#define SENTINEL  0x7FFFFFFF
#define SEGB      256         /* k_seg grid: 4096 pixels per block */

// JAX PRNG variant: 1 = threefry_partitionable (default since JAX 0.5.0).
#define JAX_PARTITIONABLE 1

__device__ __forceinline__ uint32_t rotl32(uint32_t v, int r) {
    return (v << r) | (v >> (32 - r));
}

// Threefry-2x32, 20 rounds — exact JAX schedule.
__device__ void threefry2x32(uint32_t k0, uint32_t k1, uint32_t x0, uint32_t x1,
                             uint32_t* o0, uint32_t* o1) {
    const uint32_t ks2 = k0 ^ k1 ^ 0x1BD11BDAu;
    const int R0[4] = {13, 15, 26, 6};
    const int R1[4] = {17, 29, 16, 24};
    x0 += k0; x1 += k1;
#pragma unroll
    for (int i = 0; i < 4; i++) { x0 += x1; x1 = rotl32(x1, R0[i]); x1 ^= x0; }
    x0 += k1; x1 += ks2 + 1u;
#pragma unroll
    for (int i = 0; i < 4; i++) { x0 += x1; x1 = rotl32(x1, R1[i]); x1 ^= x0; }
    x0 += ks2; x1 += k0 + 2u;
#pragma unroll
    for (int i = 0; i < 4; i++) { x0 += x1; x1 = rotl32(x1, R0[i]); x1 ^= x0; }
    x0 += k0; x1 += k1 + 3u;
#pragma unroll
    for (int i = 0; i < 4; i++) { x0 += x1; x1 = rotl32(x1, R1[i]); x1 ^= x0; }
    x0 += k1; x1 += ks2 + 4u;
#pragma unroll
    for (int i = 0; i < 4; i++) { x0 += x1; x1 = rotl32(x1, R0[i]); x1 ^= x0; }
    x0 += ks2; x1 += k0 + 5u;
    *o0 = x0; *o1 = x1;
}

// lower_bits[j] for j in [0, 1024): 32-bit random word whose low 20 bits are
// cand[j/16][j%16]. key(1) -> (0,1); k2 = split(key)[1].
__device__ uint32_t jax_cand_bits(uint32_t j) {
#if JAX_PARTITIONABLE
    uint32_t k2a, k2b;
    threefry2x32(0u, 1u, 0u, 1u, &k2a, &k2b);      // foldlike split: child 1
    uint32_t b1, b2;
    threefry2x32(k2a, k2b, 0u, j, &b1, &b2);       // iota_2x32 counts (0, j)
    return b1 ^ b2;                                // 32-bit path xors halves
#else
    uint32_t a0, a1, b0, b1;
    threefry2x32(0u, 1u, 0u, 2u, &a0, &a1);
    threefry2x32(0u, 1u, 1u, 3u, &b0, &b1);
    uint32_t k2a = a1, k2b = b1;
    uint32_t r0, r1;
    if (j < 512u) { threefry2x32(k2a, k2b, j, j + 512u, &r0, &r1); return r0; }
    else          { threefry2x32(k2a, k2b, j - 512u, j, &r0, &r1); return r1; }
#endif
}

// One pass over the mask: per-block LDS (min1, min2) per id, written to
// per-block partials — no global atomics, no init kernel needed.
// count >= 2  <=>  m2 != SENTINEL, so per-pixel counts are dropped entirely.
__global__ void k_seg(const int* __restrict__ mask, int2* __restrict__ part) {
    __shared__ int m1[KIDS], m2[KIDS];
    const int t = threadIdx.x;
    if (t < KIDS) { m1[t] = SENTINEL; m2[t] = SENTINEL; }
    __syncthreads();

    const int4* m4 = (const int4*)mask;
    const int base4 = blockIdx.x * 1024;   // 4096 pixels per block / 4
    int4 v[4];
#pragma unroll
    for (int c = 0; c < 4; c++) v[c] = m4[base4 + c * 256 + t];

#pragma unroll
    for (int c = 0; c < 4; c++) {
        const int pix0 = (base4 + c * 256 + t) * 4;
        const int ids[4] = {v[c].x, v[c].y, v[c].z, v[c].w};
#pragma unroll
        for (int j = 0; j < 4; j++) atomicMin(&m1[ids[j]], pix0 + j);
    }
    __syncthreads();
#pragma unroll
    for (int c = 0; c < 4; c++) {
        const int pix0 = (base4 + c * 256 + t) * 4;
        const int ids[4] = {v[c].x, v[c].y, v[c].z, v[c].w};
#pragma unroll
        for (int j = 0; j < 4; j++) {
            if (pix0 + j != m1[ids[j]]) atomicMin(&m2[ids[j]], pix0 + j);
        }
    }
    __syncthreads();

    if (t < KIDS) part[blockIdx.x * KIDS + t] = make_int2(m1[t], m2[t]);
}

// One block per instance id (128 threads). Wave 0 picks the random negative in
// parallel (16 lanes, one load latency, ballot+ffs), overlapped with the
// pair-merge reduction of the 256 per-block (m1,m2) partials.
__global__ void k_triplet(const float* __restrict__ sem,
                          const int* __restrict__ mask,
                          const int2* __restrict__ part,
                          float* __restrict__ per_out,
                          int* __restrict__ valid_out) {
    const int k = blockIdx.x;
    const int t = threadIdx.x;
    __shared__ int s_neg;
    __shared__ int red_lo[128], red_hi[128];
    __shared__ float red_ap[128], red_an[128];

    if (t < 64) {   // wave 0: parallel candidate selection
        int cand = 0, ok = 0;
        if (t < NCANDS) {
            const uint32_t bits = jax_cand_bits((uint32_t)(k * NCANDS + t));
            cand = (int)(bits & (uint32_t)(HW - 1));
            ok = (mask[cand] != k) ? 1 : 0;
        }
        const unsigned long long bal = __ballot(ok);
        const int pick = bal ? (__ffsll(bal) - 1) : 0;  // argmax(all-False)=0
        const int neg = __shfl(cand, pick, 64);
        if (t == 0) s_neg = neg;
    }

    // two-smallest-of-union pair merge over SEGB partials
    int lo = SENTINEL, hi = SENTINEL;
#pragma unroll
    for (int r = 0; r < SEGB / 128; r++) {
        const int2 pq = part[(r * 128 + t) * KIDS + k];
        const int nlo = min(lo, pq.x);
        const int nhi = min(max(lo, pq.x), min(hi, pq.y));
        lo = nlo; hi = nhi;
    }
    red_lo[t] = lo; red_hi[t] = hi;
    __syncthreads();
    for (int off = 64; off > 0; off >>= 1) {
        if (t < off) {
            const int a1 = red_lo[t + off], a2 = red_hi[t + off];
            const int l = red_lo[t], h = red_hi[t];
            red_lo[t] = min(l, a1);
            red_hi[t] = min(max(l, a1), min(h, a2));
        }
        __syncthreads();
    }
    const int f = red_lo[0];
    const int s = red_hi[0];
    const bool valid = (k != 0) && (s != SENTINEL);
    if (!valid) {               // uniform across block
        if (t == 0) { per_out[k] = 0.0f; valid_out[k] = 0; }
        return;
    }

    const int n = s_neg;
    float ap = 0.0f, an = 0.0f;
    if (t < BCC) {
        const size_t row = (size_t)t * (size_t)HW;
        const float a  = sem[row + f];
        const float p  = sem[row + s];
        const float nn = sem[row + n];
        const float d1 = a - p + EPSF;
        const float d2 = a - nn + EPSF;
        ap = d1 * d1;
        an = d2 * d2;
    }
    red_ap[t] = ap; red_an[t] = an;
    __syncthreads();
    for (int off = 64; off > 0; off >>= 1) {
        if (t < off) { red_ap[t] += red_ap[t + off]; red_an[t] += red_an[t + off]; }
        __syncthreads();
    }
    if (t == 0) {
        float per = sqrtf(red_ap[0]) - sqrtf(red_an[0]) + MARGINF;
        per_out[k] = per > 0.0f ? per : 0.0f;
        valid_out[k] = 1;
    }
}

__global__ void k_final(const float* __restrict__ per,
                        const int* __restrict__ valid,
                        float* __restrict__ out) {
    const int t = threadIdx.x;    // 64 threads = 1 wave
    float v = per[t];
    int   c = valid[t];
#pragma unroll
    for (int off = 32; off > 0; off >>= 1) {
        v += __shfl_down(v, off, 64);
        c += __shfl_down(c, off, 64);
    }
    if (t == 0) out[0] = (c > 0) ? (v / (float)c) : 0.0f;
}

extern "C" void kernel_launch(void* const* d_in, const int* in_sizes, int n_in,
                              void* d_out, int out_size, void* d_ws, size_t ws_size,
                              hipStream_t stream) {
    const float* sem  = (const float*)d_in[0];   // [4,19,1024,1024] f32
    const int*   mask = (const int*)d_in[1];     // [1024,1024] i32
    float* out = (float*)d_out;

    // ws layout: [SEGB*KIDS] int2 partials (128 KB) | 64 f32 per | 64 i32 valid
    int2*  part  = (int2*)d_ws;
    float* per   = (float*)((char*)d_ws + (size_t)SEGB * KIDS * sizeof(int2));
    int*   valid = (int*)((char*)per + KIDS * sizeof(float));

    k_seg<<<HW / 4096, 256, 0, stream>>>(mask, part);
    k_triplet<<<KIDS, 128, 0, stream>>>(sem, mask, part, per, valid);
    k_final<<<1, 64, 0, stream>>>(per, valid, out);
}